// Round 4
// baseline (1331947.754 us; speedup 1.0000x reference)
//
#include <hip/hip_runtime.h>

#define Tt  512
#define Hd  1024
#define Cc  10
#define THREADS 512
#define POLL_BOUND 20000

typedef short bf16x8 __attribute__((ext_vector_type(8)));
typedef float f32x4 __attribute__((ext_vector_type(4)));
typedef unsigned u32x4 __attribute__((ext_vector_type(4)));

__device__ __forceinline__ unsigned short f2bf(float f) {
  unsigned u = __builtin_bit_cast(unsigned, f);
  u = (u + 0x7FFFu + ((u >> 16) & 1u)) >> 16;   // RTNE
  return (unsigned short)u;
}
__device__ __forceinline__ float bf2f(unsigned short s) {
  unsigned u = ((unsigned)s) << 16;
  return __builtin_bit_cast(float, u);
}
__device__ __forceinline__ float sigmf_(float z) { return 1.0f / (1.0f + __expf(-z)); }
__device__ __forceinline__ float tanhf_(float z) { return 1.0f - 2.0f / (__expf(2.0f * z) + 1.0f); }

// sc0 = L1-bypass; coherence point is this XCD's L2 (groups are XCD-local by construction)
__device__ __forceinline__ void store_u32_sc0(unsigned* p, unsigned v) {
  asm volatile("global_store_dword %0, %1, off sc0" :: "v"(p), "v"(v) : "memory");
}
__device__ __forceinline__ unsigned load_u32_sc0(const unsigned* p) {
  unsigned v;
  asm volatile("global_load_dword %0, %1, off sc0\n\ts_waitcnt vmcnt(0)"
               : "=v"(v) : "v"(p) : "memory");
  return v;
}

__launch_bounds__(THREADS, 2)
__global__ void lstm_kernel(
    const float* __restrict__ x,
    const float* __restrict__ wgx, const float* __restrict__ wgh, const float* __restrict__ bg,
    const float* __restrict__ wix, const float* __restrict__ wih, const float* __restrict__ bi,
    const float* __restrict__ wfx, const float* __restrict__ wfh, const float* __restrict__ bfp,
    const float* __restrict__ wox, const float* __restrict__ woh, const float* __restrict__ bo,
    const float* __restrict__ wph, const float* __restrict__ bp,
    float* __restrict__ out,
    unsigned short* __restrict__ hbuf,   // [256][1024] bf16 (stays in each XCD's L2)
    unsigned* __restrict__ flags,        // [8][32] u32 (one 128B line per XCD)
    unsigned* __restrict__ cnt)          // [8] slot counters (agent-scope atomics)
{
  extern __shared__ char smem[];
  char*  hls  = smem;                               // [32 rows][2048B] swizzled bf16, 64KB
  float* zbuf = (float*)(smem + 65536);             // [32][128] f32, 16KB
  float* xls  = (float*)(smem + 65536 + 16384);     // [512][32] f32, 64KB (transposed x slice)
  float* wxb  = (float*)(smem + 65536 + 16384 + 65536);  // [4][32]
  float* bbl  = wxb + 128;                               // [4][32]

  __shared__ int slot_sh;

  const int tid = threadIdx.x;
  const int l   = tid & 63;
  const int w   = tid >> 6;          // wave 0..7

  // ---- discover physical XCD; claim a slot on it (group = blocks sharing an L2) ----
  unsigned xcd_r;
  asm("s_getreg_b32 %0, hwreg(HW_REG_XCC_ID, 0, 4)" : "=s"(xcd_r));
  const int g = (int)(xcd_r & 7);
  if (tid == 0) {
    unsigned s = __hip_atomic_fetch_add(&cnt[g], 1u, __ATOMIC_RELAXED,
                                        __HIP_MEMORY_SCOPE_AGENT);
    slot_sh = (int)(s & 31u);   // &31: OOB guard (co-residency forces exactly 32/XCD)
  }
  __syncthreads();
  const int j   = slot_sh;
  const int r0  = g * 32;            // batch rows owned by this XCD's group
  const int hc0 = j * 32;            // h-columns owned by this block

  // ---- init: zero LDS h (h_0 = 0) ----
  {
    u32x4 z4 = {0u,0u,0u,0u};
    #pragma unroll
    for (int i = 0; i < 8; ++i) {
      int m = tid + i * THREADS;
      *(u32x4*)(hls + m * 16) = z4;
    }
  }
  // ---- x slice -> LDS, transposed to [t][r] ----
  #pragma unroll
  for (int i = 0; i < 8; ++i) {
    int c = tid + i * THREADS;
    int r = c >> 7, t4 = (c & 127) * 4;
    f32x4 v = *(const f32x4*)(x + (size_t)(r0 + r) * Tt + t4);
    xls[(t4 + 0) * 32 + r] = v[0];
    xls[(t4 + 1) * 32 + r] = v[1];
    xls[(t4 + 2) * 32 + r] = v[2];
    xls[(t4 + 3) * 32 + r] = v[3];
  }
  // ---- wx, b slices into LDS ----
  if (tid < 128) {
    int q = tid >> 5, hcl = tid & 31;
    const float* px = (q == 0) ? wgx : (q == 1) ? wix : (q == 2) ? wfx : wox;
    const float* pb = (q == 0) ? bg  : (q == 1) ? bi  : (q == 2) ? bfp : bo;
    wxb[tid] = px[hc0 + hcl];
    bbl[tid] = pb[hc0 + hcl];
  }

  // ---- Wh slice -> register B-fragments (loaded ONCE) ----
  const int q = w >> 1;
  const float* whp = (q == 0) ? wgh : (q == 1) ? wih : (q == 2) ? wfh : woh;
  const int bcol = hc0 + ((w & 1) << 4) + (l & 15);
  const int kb = ((l >> 4) & 3) * 8;
  bf16x8 bq[32];
  #pragma unroll
  for (int kc = 0; kc < 32; ++kc) {
    bf16x8 v;
    #pragma unroll
    for (int e = 0; e < 8; ++e) {
      v[e] = (short)f2bf(whp[(kc * 32 + kb + e) * Hd + bcol]);
    }
    bq[kc] = v;
  }

  __syncthreads();

  float creg0 = 0.f, creg1 = 0.f;

  const int roff0 = (l & 15) * 2048;
  const int roff1 = roff0 + 16 * 2048;
  const int swz   = (l & 7) << 4;
  const int kboff = ((l >> 4) & 3) * 16;

  unsigned* myflags = flags + (g << 5);

  #pragma unroll 1
  for (int t = 0; t < Tt; ++t) {
    // ---- z = h @ Wh : A from LDS (swizzled), B from registers ----
    f32x4 acc0 = {0.f,0.f,0.f,0.f};
    f32x4 acc1 = {0.f,0.f,0.f,0.f};
    #pragma unroll
    for (int kc = 0; kc < 32; ++kc) {
      int boff = (kc * 64 + kboff) ^ swz;
      bf16x8 a0 = *(const bf16x8*)(hls + roff0 + boff);
      bf16x8 a1 = *(const bf16x8*)(hls + roff1 + boff);
      acc0 = __builtin_amdgcn_mfma_f32_16x16x32_bf16(a0, bq[kc], acc0, 0, 0, 0);
      acc1 = __builtin_amdgcn_mfma_f32_16x16x32_bf16(a1, bq[kc], acc1, 0, 0, 0);
    }

    // ---- acc -> zbuf ----
    {
      int colz  = (w << 4) + (l & 15);
      int rbase = ((l >> 4) & 3) * 4;
      #pragma unroll
      for (int p = 0; p < 4; ++p) {
        zbuf[(rbase + p) * 128 + colz]      = acc0[p];
        zbuf[(rbase + p + 16) * 128 + colz] = acc1[p];
      }
    }
    __syncthreads();

    // ---- gates + c update (f32), h' -> own-XCD L2 (plain cached stores) ----
    #pragma unroll
    for (int e = 0; e < 2; ++e) {
      int idx = tid + e * THREADS;
      int r = idx >> 5, hc = idx & 31;
      float xv = xls[t * 32 + r];
      float zg = zbuf[r * 128 +       hc] + xv * wxb[      hc] + bbl[      hc];
      float zi = zbuf[r * 128 +  32 + hc] + xv * wxb[ 32 + hc] + bbl[ 32 + hc];
      float zf = zbuf[r * 128 +  64 + hc] + xv * wxb[ 64 + hc] + bbl[ 64 + hc];
      float zo = zbuf[r * 128 +  96 + hc] + xv * wxb[ 96 + hc] + bbl[ 96 + hc];
      float gg = tanhf_(zg);
      float ii = sigmf_(zi);
      float ff = sigmf_(zf);
      float oo = sigmf_(zo);
      float cold = e ? creg1 : creg0;
      float cnew = gg * ii + cold * ff;
      if (e) creg1 = cnew; else creg0 = cnew;
      float hv = tanhf_(cnew) * oo;
      hbuf[(size_t)(r0 + r) * Hd + hc0 + hc] = f2bf(hv);
    }

    // ---- group barrier over the XCD's L2 ----
    __syncthreads();                     // drains every wave's h' stores (vmcnt0)
    if (tid == 0) store_u32_sc0(&myflags[j], (unsigned)(t + 1));
    if (w == 0 && l < 32) {              // only wave 0 polls (one flag line/XCD)
      const unsigned* f = &myflags[l];
      int it = 0;
      while (load_u32_sc0(f) < (unsigned)(t + 1) && it < POLL_BOUND) {
        ++it;
        __builtin_amdgcn_s_sleep(2);
      }
    }
    __syncthreads();                     // release all waves to stage

    // ---- stage h_{t+1}: async global->LDS (sc0), swizzle on global src ----
    {
      int rbase = w * 4;
      #pragma unroll
      for (int i = 0; i < 8; ++i) {
        int r = rbase + (i >> 1);
        int half = i & 1;
        char* ldsb = hls + r * 2048 + half * 1024;     // wave-uniform, linear dest
        int m = half * 64 + l;                          // dest 16B-chunk index
        int srcc = m ^ (r & 7);                         // inverse swizzle on source
        const char* gp = (const char*)hbuf + (((size_t)(r0 + r) << 10) + srcc * 8) * 2;
        __builtin_amdgcn_global_load_lds(gp, ldsb, 16, 0, 1 /* sc0 */);
      }
    }
    __syncthreads();                     // drains each wave's global_load_lds
  }

  // ---- projection + softmax: slot-0 block of each XCD ----
  if (j == 0) {
    if (tid < 320) {
      int r = tid / 10;
      int cls = tid - r * 10;
      float acc = bp[cls];
      for (int k16 = 0; k16 < 128; ++k16) {
        const unsigned short* hp =
            (const unsigned short*)(hls + r * 2048 + ((k16 * 16) ^ ((r & 7) << 4)));
        #pragma unroll
        for (int e = 0; e < 8; ++e) {
          acc += bf2f(hp[e]) * wph[(k16 * 8 + e) * Cc + cls];
        }
      }
      zbuf[r * 16 + cls] = acc;
    }
    __syncthreads();
    if (tid < 32) {
      int r = tid;
      float m = -1e30f;
      #pragma unroll
      for (int cc = 0; cc < Cc; ++cc) m = fmaxf(m, zbuf[r * 16 + cc]);
      float s = 0.f;
      float ev[Cc];
      #pragma unroll
      for (int cc = 0; cc < Cc; ++cc) { ev[cc] = __expf(zbuf[r * 16 + cc] - m); s += ev[cc]; }
      float inv = 1.0f / s;
      #pragma unroll
      for (int cc = 0; cc < Cc; ++cc) out[(r0 + r) * Cc + cc] = ev[cc] * inv;
    }
  }
}

extern "C" void kernel_launch(void* const* d_in, const int* in_sizes, int n_in,
                              void* d_out, int out_size, void* d_ws, size_t ws_size,
                              hipStream_t stream) {
  const float* x   = (const float*)d_in[0];
  const float* wgx = (const float*)d_in[1];
  const float* wgh = (const float*)d_in[2];
  const float* bg  = (const float*)d_in[3];
  const float* wix = (const float*)d_in[4];
  const float* wih = (const float*)d_in[5];
  const float* bi  = (const float*)d_in[6];
  const float* wfx = (const float*)d_in[7];
  const float* wfh = (const float*)d_in[8];
  const float* bfp = (const float*)d_in[9];
  const float* wox = (const float*)d_in[10];
  const float* woh = (const float*)d_in[11];
  const float* bo  = (const float*)d_in[12];
  const float* wph = (const float*)d_in[13];
  const float* bp  = (const float*)d_in[14];
  float* out = (float*)d_out;

  unsigned short* hbuf = (unsigned short*)d_ws;                          // 512KB
  unsigned* flags = (unsigned*)((char*)d_ws + (size_t)256 * Hd * 2);     // 1KB (8x128B)
  unsigned* cnt   = (unsigned*)((char*)d_ws + (size_t)256 * Hd * 2 + 1024);  // 32B

  hipMemsetAsync(flags, 0, 1024 + 64, stream);   // zero flags + slot counters

  size_t shmem = 65536 + 16384 + 65536 + 1024;
  hipFuncSetAttribute((const void*)lstm_kernel,
                      hipFuncAttributeMaxDynamicSharedMemorySize, (int)shmem);

  void* args[] = {
    (void*)&x,   (void*)&wgx, (void*)&wgh, (void*)&bg,
    (void*)&wix, (void*)&wih, (void*)&bi,
    (void*)&wfx, (void*)&wfh, (void*)&bfp,
    (void*)&wox, (void*)&woh, (void*)&bo,
    (void*)&wph, (void*)&bp,
    (void*)&out, (void*)&hbuf, (void*)&flags, (void*)&cnt
  };
  hipLaunchCooperativeKernel((const void*)lstm_kernel, dim3(256), dim3(512),
                             args, (unsigned)shmem, stream);
}

// Round 5
// 8487.367 us; speedup vs baseline: 156.9330x; 156.9330x over previous
//
#include <hip/hip_runtime.h>

#define Tt  512
#define Hd  1024
#define Cc  10
#define THREADS 512
#define POLL_BOUND 30000

typedef short bf16x8 __attribute__((ext_vector_type(8)));
typedef float f32x4 __attribute__((ext_vector_type(4)));
typedef unsigned u32x4 __attribute__((ext_vector_type(4)));

__device__ __forceinline__ unsigned short f2bf(float f) {
  unsigned u = __builtin_bit_cast(unsigned, f);
  u = (u + 0x7FFFu + ((u >> 16) & 1u)) >> 16;   // RTNE
  return (unsigned short)u;
}
__device__ __forceinline__ float bf2f(unsigned short s) {
  unsigned u = ((unsigned)s) << 16;
  return __builtin_bit_cast(float, u);
}
__device__ __forceinline__ float sigmf_(float z) { return 1.0f / (1.0f + __expf(-z)); }
__device__ __forceinline__ float tanhf_(float z) { return 1.0f - 2.0f / (__expf(2.0f * z) + 1.0f); }

// Atomics execute at the (XCD-local) L2 — L1 cannot serve them stale.
__device__ __forceinline__ void atomic_arrive(unsigned* p) {
  unsigned one = 1u;
  asm volatile("global_atomic_add %0, %1, off" :: "v"(p), "v"(one) : "memory");
}
__device__ __forceinline__ unsigned atomic_read_l2(unsigned* p) {
  unsigned old, zero = 0u;
  asm volatile("global_atomic_add %0, %1, %2, off sc0\n\ts_waitcnt vmcnt(0)"
               : "=&v"(old) : "v"(p), "v"(zero) : "memory");
  return old;
}
__device__ __forceinline__ void inv_l1() {
  asm volatile("buffer_inv" ::: "memory");
}

__launch_bounds__(THREADS, 2)
__global__ void lstm_kernel(
    const float* __restrict__ x,
    const float* __restrict__ wgx, const float* __restrict__ wgh, const float* __restrict__ bg,
    const float* __restrict__ wix, const float* __restrict__ wih, const float* __restrict__ bi,
    const float* __restrict__ wfx, const float* __restrict__ wfh, const float* __restrict__ bfp,
    const float* __restrict__ wox, const float* __restrict__ woh, const float* __restrict__ bo,
    const float* __restrict__ wph, const float* __restrict__ bp,
    float* __restrict__ out,
    unsigned short* __restrict__ hbuf,   // [256][1024] bf16 (lives in each XCD's L2)
    unsigned* __restrict__ ctr,          // [8] barrier counters, 128B apart
    unsigned* __restrict__ cnt)          // [8] slot-claim counters
{
  extern __shared__ char smem[];
  char*  hls  = smem;                               // [32 rows][2048B] swizzled bf16, 64KB
  float* zbuf = (float*)(smem + 65536);             // [32][128] f32, 16KB
  float* xls  = (float*)(smem + 65536 + 16384);     // [512][32] f32, 64KB (transposed x)
  float* wxb  = (float*)(smem + 65536 + 16384 + 65536);  // [4][32]
  float* bbl  = wxb + 128;                               // [4][32]

  __shared__ int slot_sh;

  const int tid = threadIdx.x;
  const int l   = tid & 63;
  const int w   = tid >> 6;          // wave 0..7

  // ---- discover physical XCD; claim a slot (group = blocks sharing an L2) ----
  unsigned xcd_r;
  asm("s_getreg_b32 %0, hwreg(HW_REG_XCC_ID, 0, 4)" : "=s"(xcd_r));
  const int g = (int)(xcd_r & 7);
  if (tid == 0) {
    unsigned s = __hip_atomic_fetch_add(&cnt[g], 1u, __ATOMIC_RELAXED,
                                        __HIP_MEMORY_SCOPE_AGENT);
    slot_sh = (int)(s & 31u);   // &31: OOB guard (co-residency forces exactly 32/XCD)
  }
  __syncthreads();
  const int j   = slot_sh;
  const int r0  = g * 32;            // batch rows owned by this XCD's group
  const int hc0 = j * 32;            // h-columns owned by this block
  unsigned* ctrp = ctr + (g << 5);   // own 128B line per XCD

  // ---- init: zero LDS h (h_0 = 0) ----
  {
    u32x4 z4 = {0u,0u,0u,0u};
    #pragma unroll
    for (int i = 0; i < 8; ++i) {
      int m = tid + i * THREADS;
      *(u32x4*)(hls + m * 16) = z4;
    }
  }
  // ---- x slice -> LDS, transposed to [t][r] ----
  #pragma unroll
  for (int i = 0; i < 8; ++i) {
    int c = tid + i * THREADS;
    int r = c >> 7, t4 = (c & 127) * 4;
    f32x4 v = *(const f32x4*)(x + (size_t)(r0 + r) * Tt + t4);
    xls[(t4 + 0) * 32 + r] = v[0];
    xls[(t4 + 1) * 32 + r] = v[1];
    xls[(t4 + 2) * 32 + r] = v[2];
    xls[(t4 + 3) * 32 + r] = v[3];
  }
  // ---- wx, b slices into LDS ----
  if (tid < 128) {
    int q = tid >> 5, hcl = tid & 31;
    const float* px = (q == 0) ? wgx : (q == 1) ? wix : (q == 2) ? wfx : wox;
    const float* pb = (q == 0) ? bg  : (q == 1) ? bi  : (q == 2) ? bfp : bo;
    wxb[tid] = px[hc0 + hcl];
    bbl[tid] = pb[hc0 + hcl];
  }

  // ---- Wh slice -> register B-fragments (loaded ONCE) ----
  const int q = w >> 1;
  const float* whp = (q == 0) ? wgh : (q == 1) ? wih : (q == 2) ? wfh : woh;
  const int bcol = hc0 + ((w & 1) << 4) + (l & 15);
  const int kb = ((l >> 4) & 3) * 8;
  bf16x8 bq[32];
  #pragma unroll
  for (int kc = 0; kc < 32; ++kc) {
    bf16x8 v;
    #pragma unroll
    for (int e = 0; e < 8; ++e) {
      v[e] = (short)f2bf(whp[(kc * 32 + kb + e) * Hd + bcol]);
    }
    bq[kc] = v;
  }

  __syncthreads();

  float creg0 = 0.f, creg1 = 0.f;
  int dead = 0;                      // fail-fast: stop polling after first timeout

  const int roff0 = (l & 15) * 2048;
  const int roff1 = roff0 + 16 * 2048;
  const int swz   = (l & 7) << 4;
  const int kboff = ((l >> 4) & 3) * 16;

  #pragma unroll 1
  for (int t = 0; t < Tt; ++t) {
    // ---- z = h @ Wh : A from LDS (swizzled), B from registers ----
    f32x4 acc0 = {0.f,0.f,0.f,0.f};
    f32x4 acc1 = {0.f,0.f,0.f,0.f};
    #pragma unroll
    for (int kc = 0; kc < 32; ++kc) {
      int boff = (kc * 64 + kboff) ^ swz;
      bf16x8 a0 = *(const bf16x8*)(hls + roff0 + boff);
      bf16x8 a1 = *(const bf16x8*)(hls + roff1 + boff);
      acc0 = __builtin_amdgcn_mfma_f32_16x16x32_bf16(a0, bq[kc], acc0, 0, 0, 0);
      acc1 = __builtin_amdgcn_mfma_f32_16x16x32_bf16(a1, bq[kc], acc1, 0, 0, 0);
    }

    // ---- acc -> zbuf ----
    {
      int colz  = (w << 4) + (l & 15);
      int rbase = ((l >> 4) & 3) * 4;
      #pragma unroll
      for (int p = 0; p < 4; ++p) {
        zbuf[(rbase + p) * 128 + colz]      = acc0[p];
        zbuf[(rbase + p + 16) * 128 + colz] = acc1[p];
      }
    }
    __syncthreads();

    // ---- gates + c update (f32), h' -> own-XCD L2 (plain cached stores) ----
    #pragma unroll
    for (int e = 0; e < 2; ++e) {
      int idx = tid + e * THREADS;
      int r = idx >> 5, hc = idx & 31;
      float xv = xls[t * 32 + r];
      float zg = zbuf[r * 128 +       hc] + xv * wxb[      hc] + bbl[      hc];
      float zi = zbuf[r * 128 +  32 + hc] + xv * wxb[ 32 + hc] + bbl[ 32 + hc];
      float zf = zbuf[r * 128 +  64 + hc] + xv * wxb[ 64 + hc] + bbl[ 64 + hc];
      float zo = zbuf[r * 128 +  96 + hc] + xv * wxb[ 96 + hc] + bbl[ 96 + hc];
      float gg = tanhf_(zg);
      float ii = sigmf_(zi);
      float ff = sigmf_(zf);
      float oo = sigmf_(zo);
      float cold = e ? creg1 : creg0;
      float cnew = gg * ii + cold * ff;
      if (e) creg1 = cnew; else creg0 = cnew;
      float hv = tanhf_(cnew) * oo;
      hbuf[(size_t)(r0 + r) * Hd + hc0 + hc] = f2bf(hv);
    }

    // ---- XCD-local barrier: counter atomics at the L2 ----
    __syncthreads();                     // drains every wave's h' stores (vmcnt0)
    if (tid == 0) {
      atomic_arrive(ctrp);
      if (!dead) {
        unsigned target = 32u * (unsigned)(t + 1);
        int it = 0;
        while (atomic_read_l2(ctrp) < target && it < POLL_BOUND) {
          ++it;
          __builtin_amdgcn_s_sleep(1);
        }
        if (it >= POLL_BOUND) dead = 1;   // fail fast, never hang
      }
    }
    __syncthreads();                     // release all waves

    // ---- L1 invalidate, then stage h_{t+1}: global->LDS from fresh L2 ----
    inv_l1();
    {
      int rbase = w * 4;
      #pragma unroll
      for (int i = 0; i < 8; ++i) {
        int r = rbase + (i >> 1);
        int half = i & 1;
        char* ldsb = hls + r * 2048 + half * 1024;     // wave-uniform, linear dest
        int m = half * 64 + l;                          // dest 16B-chunk index
        int srcc = m ^ (r & 7);                         // inverse swizzle on source
        const char* gp = (const char*)hbuf + (((size_t)(r0 + r) << 10) + srcc * 8) * 2;
        __builtin_amdgcn_global_load_lds(gp, ldsb, 16, 0, 0);
      }
    }
    __syncthreads();                     // drains each wave's global_load_lds
  }

  // ---- projection + softmax: slot-0 block of each XCD ----
  if (j == 0) {
    if (tid < 320) {
      int r = tid / 10;
      int cls = tid - r * 10;
      float acc = bp[cls];
      for (int k16 = 0; k16 < 128; ++k16) {
        const unsigned short* hp =
            (const unsigned short*)(hls + r * 2048 + ((k16 * 16) ^ ((r & 7) << 4)));
        #pragma unroll
        for (int e = 0; e < 8; ++e) {
          acc += bf2f(hp[e]) * wph[(k16 * 8 + e) * Cc + cls];
        }
      }
      zbuf[r * 16 + cls] = acc;
    }
    __syncthreads();
    if (tid < 32) {
      int r = tid;
      float m = -1e30f;
      #pragma unroll
      for (int cc = 0; cc < Cc; ++cc) m = fmaxf(m, zbuf[r * 16 + cc]);
      float s = 0.f;
      float ev[Cc];
      #pragma unroll
      for (int cc = 0; cc < Cc; ++cc) { ev[cc] = __expf(zbuf[r * 16 + cc] - m); s += ev[cc]; }
      float inv = 1.0f / s;
      #pragma unroll
      for (int cc = 0; cc < Cc; ++cc) out[(r0 + r) * Cc + cc] = ev[cc] * inv;
    }
  }
}

extern "C" void kernel_launch(void* const* d_in, const int* in_sizes, int n_in,
                              void* d_out, int out_size, void* d_ws, size_t ws_size,
                              hipStream_t stream) {
  const float* x   = (const float*)d_in[0];
  const float* wgx = (const float*)d_in[1];
  const float* wgh = (const float*)d_in[2];
  const float* bg  = (const float*)d_in[3];
  const float* wix = (const float*)d_in[4];
  const float* wih = (const float*)d_in[5];
  const float* bi  = (const float*)d_in[6];
  const float* wfx = (const float*)d_in[7];
  const float* wfh = (const float*)d_in[8];
  const float* bfp = (const float*)d_in[9];
  const float* wox = (const float*)d_in[10];
  const float* woh = (const float*)d_in[11];
  const float* bo  = (const float*)d_in[12];
  const float* wph = (const float*)d_in[13];
  const float* bp  = (const float*)d_in[14];
  float* out = (float*)d_out;

  unsigned short* hbuf = (unsigned short*)d_ws;                            // 512KB
  unsigned* ctr = (unsigned*)((char*)d_ws + (size_t)256 * Hd * 2);         // 8 x 128B
  unsigned* cnt = (unsigned*)((char*)d_ws + (size_t)256 * Hd * 2 + 1024);  // 8 x 4B

  hipMemsetAsync(ctr, 0, 1024 + 64, stream);   // zero barrier + slot counters

  size_t shmem = 65536 + 16384 + 65536 + 1024;
  hipFuncSetAttribute((const void*)lstm_kernel,
                      hipFuncAttributeMaxDynamicSharedMemorySize, (int)shmem);

  void* args[] = {
    (void*)&x,   (void*)&wgx, (void*)&wgh, (void*)&bg,
    (void*)&wix, (void*)&wih, (void*)&bi,
    (void*)&wfx, (void*)&wfh, (void*)&bfp,
    (void*)&wox, (void*)&woh, (void*)&bo,
    (void*)&wph, (void*)&bp,
    (void*)&out, (void*)&hbuf, (void*)&ctr, (void*)&cnt
  };
  hipLaunchCooperativeKernel((const void*)lstm_kernel, dim3(256), dim3(512),
                             args, (unsigned)shmem, stream);
}